// Round 1
// baseline (106.729 us; speedup 1.0000x reference)
//
#include <hip/hip_runtime.h>

// SmallSMBlock: K = Conv2d(1,9,3,'same')(image)+b per pixel; y[b] = 9-tap apply to x[b].
// Memory-bound: ideal ~72 MB traffic -> ~11.4 us floor at 6.3 TB/s.
// R3: syncless streaming version. No LDS, no __syncthreads. Each thread owns
// 1 row x 4 cols; reads its 3x6 neighborhood via aligned float4 + 2 edge
// scalars (L1 serves the 3x overlap between threads; HBM traffic unchanged).
// Batch dim split across blockIdx.z (2 z-slices x 4 batches) to double wave
// supply for latency hiding; duplicated image read absorbed by L2/L3.
// NOTE: measured dur_us includes ~86us of harness re-poison fills (2 x 256MiB
// at ~43us each, seen in rocprof top-5); kernel portion is ~14.5us pre-R3.

#define H  1024
#define W  1024
#define NB 8
#define TD 32            // tile dim (pixels)
#define SPLIT 2          // batch split across blockIdx.z
#define BPB (NB / SPLIT) // batches per block

__global__ __launch_bounds__(256, 4)
void smblock_kernel(const float* __restrict__ image,
                    const float* __restrict__ x,
                    const float* __restrict__ kw,   // (9,1,3,3)
                    const float* __restrict__ kb,   // (9,)
                    float* __restrict__ y)          // (8,1,H,W)
{
    const int tid = threadIdx.x;
    const int r   = tid >> 3;          // pixel row 0..31 within tile
    const int cg  = tid & 7;           // col group: pixel cols 4cg..4cg+3
    const int h0  = blockIdx.y * TD;
    const int w0  = blockIdx.x * TD;
    const int gw  = w0 + 4 * cg;       // 16B-aligned column of this thread's float4
    const int gh0 = h0 + r;            // this thread's pixel row
    const bool lok = (gw > 0);         // left neighbor col exists
    const bool rok = (gw + 4 < W);     // right neighbor col exists

    // ---- per-pixel predicted kernels: K[j][t] for pixels (gh0, gw+j) ----
    float K[4][9];
    #pragma unroll
    for (int t = 0; t < 9; ++t) {
        const float bt = kb[t];
        K[0][t] = bt; K[1][t] = bt; K[2][t] = bt; K[3][t] = bt;
    }

    #pragma unroll
    for (int a = 0; a < 3; ++a) {
        const int gh = gh0 + a - 1;
        float wv[6] = {0.f, 0.f, 0.f, 0.f, 0.f, 0.f};
        if ((unsigned)gh < H) {
            const float* p = image + (size_t)gh * W + gw;
            float4 m = *(const float4*)p;      // aligned global_load_dwordx4
            wv[1] = m.x; wv[2] = m.y; wv[3] = m.z; wv[4] = m.w;
            if (lok) wv[0] = p[-1];
            if (rok) wv[5] = p[4];
        }
        #pragma unroll
        for (int d = 0; d < 3; ++d) {
            #pragma unroll
            for (int t = 0; t < 9; ++t) {
                const float wgt = kw[t * 9 + 3 * a + d];   // wave-uniform -> s_load
                #pragma unroll
                for (int j = 0; j < 4; ++j)
                    K[j][t] += wgt * wv[j + d];
            }
        }
    }

    // ---- apply to this z-slice's batches; no barriers, pure streaming ----
    const int    b0  = blockIdx.z * BPB;
    const size_t pix = (size_t)gh0 * W + gw;

    #pragma unroll
    for (int bi = 0; bi < BPB; ++bi) {
        const float* xb = x + (size_t)(b0 + bi) * ((size_t)H * W);
        float a0 = 0.f, a1 = 0.f, a2 = 0.f, a3 = 0.f;

        #pragma unroll
        for (int a = 0; a < 3; ++a) {
            const int gh = gh0 + a - 1;
            float wv[6] = {0.f, 0.f, 0.f, 0.f, 0.f, 0.f};
            if ((unsigned)gh < H) {
                const float* p = xb + (size_t)gh * W + gw;
                float4 m = *(const float4*)p;
                wv[1] = m.x; wv[2] = m.y; wv[3] = m.z; wv[4] = m.w;
                if (lok) wv[0] = p[-1];
                if (rok) wv[5] = p[4];
            }
            #pragma unroll
            for (int d = 0; d < 3; ++d) {
                a0 += wv[0 + d] * K[0][3 * a + d];
                a1 += wv[1 + d] * K[1][3 * a + d];
                a2 += wv[2 + d] * K[2][3 * a + d];
                a3 += wv[3 + d] * K[3][3 * a + d];
            }
        }
        float4 o; o.x = a0; o.y = a1; o.z = a2; o.w = a3;
        *(float4*)(y + (size_t)(b0 + bi) * ((size_t)H * W) + pix) = o;  // dwordx4 store
    }
}

extern "C" void kernel_launch(void* const* d_in, const int* in_sizes, int n_in,
                              void* d_out, int out_size, void* d_ws, size_t ws_size,
                              hipStream_t stream)
{
    const float* image = (const float*)d_in[0];  // (1,1024,1024)
    const float* x     = (const float*)d_in[1];  // (8,1,1024,1024)
    const float* kw    = (const float*)d_in[2];  // (9,1,3,3)
    const float* kb    = (const float*)d_in[3];  // (9,)
    float* y = (float*)d_out;                    // (8,1,1024,1024)

    dim3 grid(W / TD, H / TD, SPLIT);
    smblock_kernel<<<grid, 256, 0, stream>>>(image, x, kw, kb, y);
}

// Round 3
// 99.872 us; speedup vs baseline: 1.0687x; 1.0687x over previous
//
#include <hip/hip_runtime.h>

// SmallSMBlock: K = Conv2d(1,9,3,'same')(image)+b per pixel; y[b] = 9-tap apply to x[b].
// Memory-bound: ideal ~68 MB traffic -> ~11.4 us floor at 6.3 TB/s.
// R5 = R4 with the nontemporal-store type fixed (native ext_vector_type, not
// HIP_vector_type float4 — clang builtin rejects class types).
// R4 idea: pair-wise batch staging (4 syncs/block instead of 8) + nt y-stores
// (keep streaming writes from evicting x halos in L2).
// R3 post-mortem: syncless/global-direct regressed (10 VMEM instr/thread/batch vs
// R2's 2; TA-pipe issue-bound, not byte-bound). LDS staging = instruction economy.
// NOTE: measured dur_us includes ~86us of harness re-poison fills (2 x 256MiB at
// ~43us, 78% peak, visible in rocprof top-5); controllable kernel part ~14.5us.

#define H  1024
#define W  1024
#define NB 8
#define TD 32            // tile dim (pixels)
#define TP 34            // padded tile dim
#define LS 36            // LDS row stride (floats): keeps 4*cg reads 16B-aligned
#define LT (TP * LS)     // floats per staged tile (34*36 = 1224)

typedef float f32x4 __attribute__((ext_vector_type(4)));   // NT-store-compatible

__global__ __launch_bounds__(256)
void smblock_kernel(const float* __restrict__ image,
                    const float* __restrict__ x,
                    const float* __restrict__ kw,   // (9,1,3,3)
                    const float* __restrict__ kb,   // (9,)
                    float* __restrict__ y)          // (8,1,H,W)
{
    __shared__ float simg[LT];
    __shared__ float sx[4][LT];          // pair-wise double buffer

    const int h0  = blockIdx.y * TD;
    const int w0  = blockIdx.x * TD;
    const int tid = threadIdx.x;
    const int r   = tid >> 3;      // pixel row 0..31
    const int cg  = tid & 7;       // col group: pixel cols 4cg..4cg+3

    // interior global offset (16B aligned: w0+4cg is a multiple of 4)
    const size_t gint = (size_t)(h0 + r) * W + (w0 + 4 * cg);
    const int    lint = (r + 1) * LS + (4 * cg + 1);   // LDS dest (padded coords)

    // ---- halo assignment: 132 border elements of the 34x34 padded tile ----
    int hr = -1, hc = -1;
    {
        const int wv = tid >> 6, ln = tid & 63;
        if      (wv == 0) { if (ln < TP) { hr = 0;      hc = ln;     } }
        else if (wv == 1) { if (ln < TP) { hr = TP - 1; hc = ln;     } }
        else if (wv == 2) { if (ln < TD) { hr = ln + 1; hc = 0;      } }
        else              { if (ln < TD) { hr = ln + 1; hc = TP - 1; } }
    }
    const bool has_halo = (hr >= 0);
    const int  gh = h0 + hr - 1, gw = w0 + hc - 1;
    const bool hin = has_halo && ((unsigned)gh < H) && ((unsigned)gw < W);
    const size_t ghalo = (size_t)gh * W + gw;
    const int    lhalo = hr * LS + hc;

    const size_t HW = (size_t)H * W;

    // ---- stage image + batches 0,1 ----
    {
        float4 iv = *(const float4*)(image + gint);
        float4 x0 = *(const float4*)(x + gint);
        float4 x1 = *(const float4*)(x + HW + gint);
        float ihv = hin ? image[ghalo]   : 0.f;
        float h0v = hin ? x[ghalo]       : 0.f;
        float h1v = hin ? x[HW + ghalo]  : 0.f;
        simg[lint]  = iv.x; simg[lint+1]  = iv.y; simg[lint+2]  = iv.z; simg[lint+3]  = iv.w;
        sx[0][lint] = x0.x; sx[0][lint+1] = x0.y; sx[0][lint+2] = x0.z; sx[0][lint+3] = x0.w;
        sx[1][lint] = x1.x; sx[1][lint+1] = x1.y; sx[1][lint+2] = x1.z; sx[1][lint+3] = x1.w;
        if (has_halo) { simg[lhalo] = ihv; sx[0][lhalo] = h0v; sx[1][lhalo] = h1v; }
    }
    __syncthreads();

    // ---- per-pixel predicted kernels: K[j][t] for pixels (r, 4cg+j), taps t ----
    float K[4][9];
    #pragma unroll
    for (int j = 0; j < 4; ++j)
        #pragma unroll
        for (int t = 0; t < 9; ++t) K[j][t] = kb[t];

    #pragma unroll
    for (int a = 0; a < 3; ++a) {
        const float* row = &simg[(r + a) * LS + 4 * cg];
        float4 f4 = *(const float4*)row;        // 16B-aligned (LS=36)
        float2 f2 = *(const float2*)(row + 4);
        float wv[6] = { f4.x, f4.y, f4.z, f4.w, f2.x, f2.y };
        #pragma unroll
        for (int d = 0; d < 3; ++d)
            #pragma unroll
            for (int t = 0; t < 9; ++t) {
                float wgt = kw[t * 9 + 3 * a + d];   // wave-uniform -> s_load
                #pragma unroll
                for (int j = 0; j < 4; ++j)
                    K[j][t] += wgt * wv[j + d];
            }
    }

    // ---- apply per batch pair; one sync per 2 batches ----
    #pragma unroll
    for (int p = 0; p < NB / 2; ++p) {
        const int base = (p & 1) * 2;          // buffers holding batches 2p, 2p+1

        // prefetch next pair into registers (overlaps compute)
        float4 pv0, pv1; float ph0 = 0.f, ph1 = 0.f;
        if (p + 1 < NB / 2) {
            const float* xn0 = x + (size_t)(2 * p + 2) * HW;
            const float* xn1 = x + (size_t)(2 * p + 3) * HW;
            pv0 = *(const float4*)(xn0 + gint);
            pv1 = *(const float4*)(xn1 + gint);
            if (hin) { ph0 = xn0[ghalo]; ph1 = xn1[ghalo]; }
        }

        #pragma unroll
        for (int q = 0; q < 2; ++q) {
            const float* sb = sx[base + q];
            float a0 = 0.f, a1 = 0.f, a2 = 0.f, a3 = 0.f;
            #pragma unroll
            for (int a = 0; a < 3; ++a) {
                const float* row = &sb[(r + a) * LS + 4 * cg];
                float4 f4 = *(const float4*)row;    // ds_read_b128
                float2 f2 = *(const float2*)(row + 4);
                float wv[6] = { f4.x, f4.y, f4.z, f4.w, f2.x, f2.y };
                #pragma unroll
                for (int d = 0; d < 3; ++d) {
                    a0 += wv[0 + d] * K[0][3 * a + d];
                    a1 += wv[1 + d] * K[1][3 * a + d];
                    a2 += wv[2 + d] * K[2][3 * a + d];
                    a3 += wv[3 + d] * K[3][3 * a + d];
                }
            }
            f32x4 o = { a0, a1, a2, a3 };
            // nt store: y is write-once, keep it from evicting x halos in L2
            __builtin_nontemporal_store(o,
                (f32x4*)(y + (size_t)(2 * p + q) * HW + gint));
        }

        if (p + 1 < NB / 2) {
            float* d0 = sx[base ^ 2];
            float* d1 = sx[(base ^ 2) + 1];
            d0[lint]   = pv0.x; d0[lint+1] = pv0.y; d0[lint+2] = pv0.z; d0[lint+3] = pv0.w;
            d1[lint]   = pv1.x; d1[lint+1] = pv1.y; d1[lint+2] = pv1.z; d1[lint+3] = pv1.w;
            if (has_halo) { d0[lhalo] = ph0; d1[lhalo] = ph1; }
            __syncthreads();
        }
    }
}

extern "C" void kernel_launch(void* const* d_in, const int* in_sizes, int n_in,
                              void* d_out, int out_size, void* d_ws, size_t ws_size,
                              hipStream_t stream)
{
    const float* image = (const float*)d_in[0];  // (1,1024,1024)
    const float* x     = (const float*)d_in[1];  // (8,1,1024,1024)
    const float* kw    = (const float*)d_in[2];  // (9,1,3,3)
    const float* kb    = (const float*)d_in[3];  // (9,)
    float* y = (float*)d_out;                    // (8,1,1024,1024)

    dim3 grid(W / TD, H / TD);
    smblock_kernel<<<grid, 256, 0, stream>>>(image, x, kw, kb, y);
}